// Round 3
// baseline (162.560 us; speedup 1.0000x reference)
//
#include <hip/hip_runtime.h>

// Problem constants (match reference)
constexpr int B = 1024;
constexpr int C = 1024;
constexpr int K = 20;
constexpr int L = 2048;
constexpr int V = 80;
constexpr int TK = 3 * K;  // 60

// Output layout (flat floats): w [B,V] @0 ; kappa [B,K] @B*V ; phi [B,L+1] @B*V+B*K
constexpr size_t OUT_KAPPA = (size_t)B * V;            // 81920
constexpr size_t OUT_PHI   = OUT_KAPPA + (size_t)B * K; // 102400

// ---------------- K1: params + phi (per-b block) ----------------
__global__ __launch_bounds__(256)
void params_phi_kernel(const float* __restrict__ x,
                       const float* __restrict__ W,
                       const float* __restrict__ bias,
                       const float* __restrict__ kappa_old,
                       const int*   __restrict__ text_lens,
                       float* __restrict__ out) {
    const int b = blockIdx.x;
    const int t = threadIdx.x;

    __shared__ float lds_x[C];      // 4 KB
    __shared__ float lds_abk[TK];   // alpha[0:20], beta[20:40], kappa[40:60]

    // stage x[b,:] (coalesced float4)
    reinterpret_cast<float4*>(lds_x)[t] =
        reinterpret_cast<const float4*>(x + (size_t)b * C)[t];
    __syncthreads();

    // params = exp(x@W + b)
    {
        const int g   = t >> 2;   // column 0..63 (use 0..59)
        const int sub = t & 3;
        float acc = 0.0f;
        if (g < TK) {
            const float* Wg = W + g;
            #pragma unroll 8
            for (int i = 0; i < C / 4; ++i) {
                const int c = sub + 4 * i;
                acc += lds_x[c] * Wg[c * TK];
            }
        }
        acc += __shfl_xor(acc, 1);
        acc += __shfl_xor(acc, 2);
        if (sub == 0 && g < TK) {
            const float p = __expf(acc + bias[g]);
            if (g >= 2 * K) {
                const int k = g - 2 * K;
                const float kap = kappa_old[(size_t)b * K + k] + p;
                lds_abk[g] = kap;
                out[OUT_KAPPA + (size_t)b * K + k] = kap;
            } else {
                lds_abk[g] = p;
            }
        }
    }
    __syncthreads();

    // phi[l] = scale * sum_k alpha_k * exp(-beta_k*(kappa_k-l)^2), l in [0, L]
    {
        float s[8];
        #pragma unroll
        for (int j = 0; j < 8; ++j) s[j] = 0.0f;
        #pragma unroll
        for (int k = 0; k < K; ++k) {
            const float a  = lds_abk[k];
            const float be = lds_abk[K + k];
            const float kp = lds_abk[2 * K + k];
            #pragma unroll
            for (int j = 0; j < 8; ++j) {
                const float d = kp - (float)(t + (j << 8));
                s[j] += a * __expf(-be * d * d);
            }
        }
        const float scale = 2048.0f / (float)text_lens[b];
        float* out_phi = out + OUT_PHI + (size_t)b * (L + 1);
        #pragma unroll
        for (int j = 0; j < 8; ++j)
            out_phi[t + (j << 8)] = s[j] * scale;
        if (t == 0) {  // tail l = 2048
            float sv = 0.0f;
            #pragma unroll
            for (int k = 0; k < K; ++k) {
                const float d = lds_abk[2 * K + k] - 2048.0f;
                sv += lds_abk[k] * __expf(-lds_abk[K + k] * d * d);
            }
            out_phi[L] = sv * scale;
        }
    }
}

// ---------------- K2: pure streaming w = phi . onehots ----------------
__global__ __launch_bounds__(512, 6)
void window_stream_kernel(const float* __restrict__ onehots,
                          float* __restrict__ out) {
    const int b = blockIdx.x;
    const int t = threadIdx.x;

    __shared__ float lds_phi[L];   // 8 KB (phi[2048] tail not needed here)
    __shared__ float lds_w[V];     // 320 B

    // load phi[b][0:2048] (written by K1; 4-byte aligned rows -> dword loads)
    {
        const float* phi_src = out + OUT_PHI + (size_t)b * (L + 1);
        #pragma unroll
        for (int i = 0; i < L / 512; ++i)
            lds_phi[t + i * 512] = phi_src[t + i * 512];
    }
    if (t < V) lds_w[t] = 0.0f;
    __syncthreads();

    const float4* oh = reinterpret_cast<const float4*>(onehots + (size_t)b * L * V);

    // 40960 float4 chunks / 512 threads = 80 chunks/thread.
    // One-hot rows: each chunk has at most one nonzero, value exactly 1.0f.
    #define PROC(vv, jj) {                                                  \
        const float s_ = vv.x + vv.y + vv.z + vv.w;                         \
        if (s_ != 0.0f) {                                                   \
            const int i_ = t + (jj) * 512;                                  \
            const float ph = lds_phi[i_ / 20];                              \
            const int v0 = (i_ % 20) * 4;                                   \
            const int jo = (int)(vv.y + 2.0f * vv.z + 3.0f * vv.w);         \
            atomicAdd(&lds_w[v0 + jo], ph * s_);                            \
        } }

    // 8-deep register pipeline: two quads A/B, rolling refill
    float4 a0 = oh[t];            float4 a1 = oh[t + 512];
    float4 a2 = oh[t + 1024];     float4 a3 = oh[t + 1536];
    float4 b0 = oh[t + 2048];     float4 b1 = oh[t + 2560];
    float4 b2 = oh[t + 3072];     float4 b3 = oh[t + 3584];

    #pragma unroll 1
    for (int q = 0; q < 20; q += 2) {      // quad q = chunks j = 4q..4q+3
        const int ja = q * 4;
        PROC(a0, ja);     PROC(a1, ja + 1);
        PROC(a2, ja + 2); PROC(a3, ja + 3);
        if (q + 2 < 20) {
            const int na = t + (q + 2) * 2048;
            a0 = oh[na];        a1 = oh[na + 512];
            a2 = oh[na + 1024]; a3 = oh[na + 1536];
        }
        const int jb = ja + 4;
        PROC(b0, jb);     PROC(b1, jb + 1);
        PROC(b2, jb + 2); PROC(b3, jb + 3);
        if (q + 3 < 20) {
            const int nb = t + (q + 3) * 2048;
            b0 = oh[nb];        b1 = oh[nb + 512];
            b2 = oh[nb + 1024]; b3 = oh[nb + 1536];
        }
    }
    #undef PROC

    __syncthreads();
    if (t < V) out[(size_t)b * V + t] = lds_w[t];
}

extern "C" void kernel_launch(void* const* d_in, const int* in_sizes, int n_in,
                              void* d_out, int out_size, void* d_ws, size_t ws_size,
                              hipStream_t stream) {
    const float* x         = (const float*)d_in[0];
    const float* W         = (const float*)d_in[1];
    const float* bias      = (const float*)d_in[2];
    const float* kappa_old = (const float*)d_in[3];
    const float* onehots   = (const float*)d_in[4];
    const int*   text_lens = (const int*)d_in[5];
    float* out = (float*)d_out;

    params_phi_kernel<<<B, 256, 0, stream>>>(x, W, bias, kappa_old, text_lens, out);
    window_stream_kernel<<<B, 512, 0, stream>>>(onehots, out);
}

// Round 4
// 130.753 us; speedup vs baseline: 1.2433x; 1.2433x over previous
//
#include <hip/hip_runtime.h>

typedef float f32x4 __attribute__((ext_vector_type(4)));

// Problem constants
constexpr int B = 1024;
constexpr int C = 1024;
constexpr int K = 20;
constexpr int L = 2048;
constexpr int V = 80;
constexpr int TK = 3 * K;  // 60

// Output layout: w [B,V] @0 ; kappa [B,K] @B*V ; phi [B,L+1] @B*V+B*K
constexpr size_t OUT_KAPPA = (size_t)B * V;
constexpr size_t OUT_PHI   = OUT_KAPPA + (size_t)B * K;

__global__ __launch_bounds__(256)
void window_fused_kernel(const float* __restrict__ x,
                         const float* __restrict__ W,
                         const float* __restrict__ bias,
                         const float* __restrict__ kappa_old,
                         const float* __restrict__ onehots,
                         const int*   __restrict__ text_lens,
                         float* __restrict__ out) {
    const int b = blockIdx.x;
    const int t = threadIdx.x;

    __shared__ float lds_x[C];           // 4 KB
    __shared__ float lds_phi[L];         // 8 KB
    __shared__ float lds_abk[TK];        // alpha/beta/kappa
    __shared__ float lds_part[4][TK];    // GEMM cross-wave partials
    __shared__ float lds_w[V];

    const f32x4* oh = reinterpret_cast<const f32x4*>(onehots + (size_t)b * L * V);

    // ---- Early prefetch: 8 KB/wave in flight while the prefix runs ----
    f32x4 a0 = __builtin_nontemporal_load(oh + t);
    f32x4 a1 = __builtin_nontemporal_load(oh + t + 256);
    f32x4 a2 = __builtin_nontemporal_load(oh + t + 512);
    f32x4 a3 = __builtin_nontemporal_load(oh + t + 768);
    f32x4 b0 = __builtin_nontemporal_load(oh + t + 1024);
    f32x4 b1 = __builtin_nontemporal_load(oh + t + 1280);
    f32x4 b2 = __builtin_nontemporal_load(oh + t + 1536);
    f32x4 b3 = __builtin_nontemporal_load(oh + t + 1792);

    // ---- stage x[b,:] ----
    reinterpret_cast<float4*>(lds_x)[t] =
        reinterpret_cast<const float4*>(x + (size_t)b * C)[t];
    if (t < V) lds_w[t] = 0.0f;
    __syncthreads();

    // ---- GEMM: wave sub = t>>6 covers c in [sub*256, sub*256+256);
    //      lane g = t&63 owns output column g (coalesced W reads) ----
    {
        const int sub = t >> 6;
        const int g   = t & 63;
        if (g < TK) {
            const int c0 = sub * 256;
            const float* pW = W + (size_t)c0 * TK + g;
            float acc = 0.0f;
            #pragma unroll 16
            for (int i = 0; i < 256; ++i)
                acc += lds_x[c0 + i] * pW[(size_t)i * TK];
            lds_part[sub][g] = acc;
        }
    }
    __syncthreads();
    if (t < TK) {
        const float dot = lds_part[0][t] + lds_part[1][t]
                        + lds_part[2][t] + lds_part[3][t];
        const float p = __expf(dot + bias[t]);
        float v = p;
        if (t >= 2 * K) {
            const int k = t - 2 * K;
            v = kappa_old[(size_t)b * K + k] + p;
            out[OUT_KAPPA + (size_t)b * K + k] = v;
        }
        lds_abk[t] = v;
    }
    __syncthreads();

    // ---- phi[l] = scale * sum_k alpha_k * exp(-beta_k*(kappa_k-l)^2) ----
    {
        float s[8];
        #pragma unroll
        for (int j = 0; j < 8; ++j) s[j] = 0.0f;
        #pragma unroll
        for (int k = 0; k < K; ++k) {
            const float a  = lds_abk[k];
            const float be = lds_abk[K + k];
            const float kp = lds_abk[2 * K + k];
            #pragma unroll
            for (int j = 0; j < 8; ++j) {
                const float d = kp - (float)(t + (j << 8));
                s[j] += a * __expf(-be * d * d);
            }
        }
        const float scale = 2048.0f / (float)text_lens[b];
        float* out_phi = out + OUT_PHI + (size_t)b * (L + 1);
        #pragma unroll
        for (int j = 0; j < 8; ++j) {
            const int l = t + (j << 8);
            const float v = s[j] * scale;
            lds_phi[l] = v;
            out_phi[l] = v;
        }
        if (t == 0) {  // tail l = 2048 (output only)
            float sv = 0.0f;
            #pragma unroll
            for (int k = 0; k < K; ++k) {
                const float d = lds_abk[2 * K + k] - 2048.0f;
                sv += lds_abk[k] * __expf(-lds_abk[K + k] * d * d);
            }
            out_phi[L] = sv * scale;
        }
    }
    __syncthreads();

    // ---- stream: w[v] += phi[l] * onehots[b,l,v] ----
    {
        // one-hot rows: each 16B chunk holds at most one 1.0f
        #define PROC(vv, ii) {                                          \
            const float s_ = vv.x + vv.y + vv.z + vv.w;                 \
            if (s_ != 0.0f) {                                           \
                const int i_ = (ii);                                    \
                const int l_ = i_ / 20;                                 \
                const int v0 = (i_ - l_ * 20) * 4;                      \
                const int jo = (int)(vv.y + 2.0f * vv.z + 3.0f * vv.w); \
                atomicAdd(&lds_w[v0 + jo], lds_phi[l_]);                \
            } }

        // 160 chunks/thread = 40 quads, A/B double-buffered (8 in flight)
        #pragma unroll 1
        for (int q = 0; q < 40; q += 2) {
            const int ia = t + (q << 10);
            PROC(a0, ia);       PROC(a1, ia + 256);
            PROC(a2, ia + 512); PROC(a3, ia + 768);
            if (q + 2 < 40) {
                const int na = t + ((q + 2) << 10);
                a0 = __builtin_nontemporal_load(oh + na);
                a1 = __builtin_nontemporal_load(oh + na + 256);
                a2 = __builtin_nontemporal_load(oh + na + 512);
                a3 = __builtin_nontemporal_load(oh + na + 768);
            }
            const int ib = ia + 1024;
            PROC(b0, ib);       PROC(b1, ib + 256);
            PROC(b2, ib + 512); PROC(b3, ib + 768);
            if (q + 3 < 40) {
                const int nb = t + ((q + 3) << 10);
                b0 = __builtin_nontemporal_load(oh + nb);
                b1 = __builtin_nontemporal_load(oh + nb + 256);
                b2 = __builtin_nontemporal_load(oh + nb + 512);
                b3 = __builtin_nontemporal_load(oh + nb + 768);
            }
        }
        #undef PROC
    }
    __syncthreads();

    if (t < V) out[(size_t)b * V + t] = lds_w[t];
}

extern "C" void kernel_launch(void* const* d_in, const int* in_sizes, int n_in,
                              void* d_out, int out_size, void* d_ws, size_t ws_size,
                              hipStream_t stream) {
    const float* x         = (const float*)d_in[0];
    const float* W         = (const float*)d_in[1];
    const float* bias      = (const float*)d_in[2];
    const float* kappa_old = (const float*)d_in[3];
    const float* onehots   = (const float*)d_in[4];
    const int*   text_lens = (const int*)d_in[5];
    float* out = (float*)d_out;

    window_fused_kernel<<<B, 256, 0, stream>>>(x, W, bias, kappa_old,
                                               onehots, text_lens, out);
}

// Round 5
// 128.187 us; speedup vs baseline: 1.2681x; 1.0200x over previous
//
#include <hip/hip_runtime.h>

typedef float f32x4 __attribute__((ext_vector_type(4)));

// Problem constants
constexpr int B = 1024;
constexpr int C = 1024;
constexpr int K = 20;
constexpr int L = 2048;
constexpr int V = 80;
constexpr int TK = 3 * K;  // 60

// Output layout: w [B,V] @0 ; kappa [B,K] @B*V ; phi [B,L+1] @B*V+B*K
constexpr size_t OUT_KAPPA = (size_t)B * V;
constexpr size_t OUT_PHI   = OUT_KAPPA + (size_t)B * K;

#define NTLOAD(p) __builtin_nontemporal_load(p)

__global__ __launch_bounds__(256, 4)
void window_fused_kernel(const float* __restrict__ x,
                         const float* __restrict__ W,
                         const float* __restrict__ bias,
                         const float* __restrict__ kappa_old,
                         const float* __restrict__ onehots,
                         const int*   __restrict__ text_lens,
                         float* __restrict__ out) {
    const int b = blockIdx.x;
    const int t = threadIdx.x;

    __shared__ float lds_x[C];           // 4 KB
    __shared__ float lds_phi[L];         // 8 KB
    __shared__ float lds_abk[TK];        // alpha/beta/kappa
    __shared__ float lds_part[4][TK];    // GEMM cross-wave partials
    __shared__ float lds_w[V];

    const f32x4* oh = reinterpret_cast<const f32x4*>(onehots + (size_t)b * L * V);

    // ---- Early prefetch: quads A,B,C (12 KB/lane-group in flight across the
    //      whole prefix; 192 KB/CU ~= 7.8 us of BW-time) ----
    f32x4 A0 = NTLOAD(oh + t);         f32x4 A1 = NTLOAD(oh + t + 256);
    f32x4 A2 = NTLOAD(oh + t + 512);   f32x4 A3 = NTLOAD(oh + t + 768);
    f32x4 B0 = NTLOAD(oh + t + 1024);  f32x4 B1 = NTLOAD(oh + t + 1280);
    f32x4 B2 = NTLOAD(oh + t + 1536);  f32x4 B3 = NTLOAD(oh + t + 1792);
    f32x4 C0 = NTLOAD(oh + t + 2048);  f32x4 C1 = NTLOAD(oh + t + 2304);
    f32x4 C2 = NTLOAD(oh + t + 2560);  f32x4 C3 = NTLOAD(oh + t + 2816);

    // ---- stage x[b,:] ----
    reinterpret_cast<float4*>(lds_x)[t] =
        reinterpret_cast<const float4*>(x + (size_t)b * C)[t];
    if (t < V) lds_w[t] = 0.0f;
    __syncthreads();

    // ---- GEMM: wave sub covers 256 rows of C; lane g owns column g ----
    {
        const int sub = t >> 6;
        const int g   = t & 63;
        if (g < TK) {
            const int c0 = sub * 256;
            const float* pW = W + (size_t)c0 * TK + g;
            float acc = 0.0f;
            #pragma unroll 16
            for (int i = 0; i < 256; ++i)
                acc += lds_x[c0 + i] * pW[(size_t)i * TK];
            lds_part[sub][g] = acc;
        }
    }
    __syncthreads();
    if (t < TK) {
        const float dot = lds_part[0][t] + lds_part[1][t]
                        + lds_part[2][t] + lds_part[3][t];
        const float p = __expf(dot + bias[t]);
        float v = p;
        if (t >= 2 * K) {
            const int k = t - 2 * K;
            v = kappa_old[(size_t)b * K + k] + p;
            out[OUT_KAPPA + (size_t)b * K + k] = v;
        }
        lds_abk[t] = v;
    }
    __syncthreads();

    // ---- 4th prefetch quad between GEMM and phi ----
    f32x4 D0 = NTLOAD(oh + t + 3072);  f32x4 D1 = NTLOAD(oh + t + 3328);
    f32x4 D2 = NTLOAD(oh + t + 3584);  f32x4 D3 = NTLOAD(oh + t + 3840);

    // ---- phi[l] = scale * sum_k alpha_k * exp(-beta_k*(kappa_k-l)^2) ----
    {
        float s[8];
        #pragma unroll
        for (int j = 0; j < 8; ++j) s[j] = 0.0f;
        #pragma unroll
        for (int k = 0; k < K; ++k) {
            const float a  = lds_abk[k];
            const float be = lds_abk[K + k];
            const float kp = lds_abk[2 * K + k];
            #pragma unroll
            for (int j = 0; j < 8; ++j) {
                const float d = kp - (float)(t + (j << 8));
                s[j] += a * __expf(-be * d * d);
            }
        }
        const float scale = 2048.0f / (float)text_lens[b];
        float* out_phi = out + OUT_PHI + (size_t)b * (L + 1);
        #pragma unroll
        for (int j = 0; j < 8; ++j) {
            const int l = t + (j << 8);
            const float v = s[j] * scale;
            lds_phi[l] = v;
            out_phi[l] = v;
        }
        if (t == 0) {  // tail l = 2048 (output only)
            float sv = 0.0f;
            #pragma unroll
            for (int k = 0; k < K; ++k) {
                const float d = lds_abk[2 * K + k] - 2048.0f;
                sv += lds_abk[k] * __expf(-lds_abk[K + k] * d * d);
            }
            out_phi[L] = sv * scale;
        }
    }
    __syncthreads();

    // ---- stream: w[v] += phi[l] * onehots[b,l,v]; 16-deep pipeline ----
    {
        // one-hot rows: each 16B chunk holds at most one element, exactly 1.0f
        #define PROC(vv, ii) {                                          \
            const float s_ = vv.x + vv.y + vv.z + vv.w;                 \
            if (s_ != 0.0f) {                                           \
                const int i_ = (ii);                                    \
                const int l_ = i_ / 20;                                 \
                const int v0 = (i_ - l_ * 20) * 4;                      \
                const int jo = (int)(vv.y + 2.0f * vv.z + 3.0f * vv.w); \
                atomicAdd(&lds_w[v0 + jo], lds_phi[l_]);                \
            } }
        #define REFILL(Q, base) {                                       \
            Q##0 = NTLOAD(oh + (base));       Q##1 = NTLOAD(oh + (base) + 256); \
            Q##2 = NTLOAD(oh + (base) + 512); Q##3 = NTLOAD(oh + (base) + 768); }

        // 160 chunks/thread = 40 quads; A/B/C/D rotating, 12-16 loads in flight
        #pragma unroll 1
        for (int q = 0; q < 40; q += 4) {
            const int ia = t + (q << 10);
            PROC(A0, ia);       PROC(A1, ia + 256);
            PROC(A2, ia + 512); PROC(A3, ia + 768);
            if (q + 4 < 40) REFILL(A, t + ((q + 4) << 10));
            const int ib = ia + 1024;
            PROC(B0, ib);       PROC(B1, ib + 256);
            PROC(B2, ib + 512); PROC(B3, ib + 768);
            if (q + 5 < 40) REFILL(B, t + ((q + 5) << 10));
            const int ic = ia + 2048;
            PROC(C0, ic);       PROC(C1, ic + 256);
            PROC(C2, ic + 512); PROC(C3, ic + 768);
            if (q + 6 < 40) REFILL(C, t + ((q + 6) << 10));
            const int id = ia + 3072;
            PROC(D0, id);       PROC(D1, id + 256);
            PROC(D2, id + 512); PROC(D3, id + 768);
            if (q + 7 < 40) REFILL(D, t + ((q + 7) << 10));
        }
        #undef REFILL
        #undef PROC
    }
    __syncthreads();

    if (t < V) out[(size_t)b * V + t] = lds_w[t];
}

extern "C" void kernel_launch(void* const* d_in, const int* in_sizes, int n_in,
                              void* d_out, int out_size, void* d_ws, size_t ws_size,
                              hipStream_t stream) {
    const float* x         = (const float*)d_in[0];
    const float* W         = (const float*)d_in[1];
    const float* bias      = (const float*)d_in[2];
    const float* kappa_old = (const float*)d_in[3];
    const float* onehots   = (const float*)d_in[4];
    const int*   text_lens = (const int*)d_in[5];
    float* out = (float*)d_out;

    window_fused_kernel<<<B, 256, 0, stream>>>(x, W, bias, kappa_old,
                                               onehots, text_lens, out);
}